// Round 13
// baseline (180.769 us; speedup 1.0000x reference)
//
#include <hip/hip_runtime.h>
#include <cstdint>
#include <cstddef>

#define EPSV 1e-5f
constexpr int B_ = 8;
constexpr int C_ = 512;
constexpr int N_ = 2048;

typedef _Float16 f16x8 __attribute__((ext_vector_type(8)));
typedef float    f32x4 __attribute__((ext_vector_type(4)));

__device__ __forceinline__ unsigned short f16b(float f) {
    _Float16 h = (_Float16)f;
    return __builtin_bit_cast(unsigned short, h);
}

__device__ __forceinline__ void gload_lds16(const void* g, void* l) {
    __builtin_amdgcn_global_load_lds(
        (const __attribute__((address_space(1))) void*)g,
        (__attribute__((address_space(3))) void*)l, 16, 0, 0);
}

// ---------------------------------------------------------------------------
// x (B,C,N) fp32 -> xT (B,N,C) fp16
// ---------------------------------------------------------------------------
__global__ __launch_bounds__(256) void split_x_kernel(
    const float* __restrict__ x, unsigned short* __restrict__ xh)
{
    __shared__ float T[64][65];
    const int b = blockIdx.z, c0 = blockIdx.y * 64, n0 = blockIdx.x * 64;
    const float* xb = x + ((size_t)b * C_ + c0) * N_ + n0;
    const int tid = threadIdx.x;
    const int lr = tid >> 4;
    const int lcn = (tid & 15) * 4;
#pragma unroll
    for (int it = 0; it < 4; ++it) {
        float4 v = *(const float4*)&xb[(size_t)(lr + 16 * it) * N_ + lcn];
        T[lr + 16 * it][lcn + 0] = v.x;
        T[lr + 16 * it][lcn + 1] = v.y;
        T[lr + 16 * it][lcn + 2] = v.z;
        T[lr + 16 * it][lcn + 3] = v.w;
    }
    __syncthreads();
    const int n = tid >> 2, cb = (tid & 3) * 16;
    alignas(16) unsigned short h[16];
#pragma unroll
    for (int i = 0; i < 16; ++i)
        h[i] = f16b(T[cb + i][n]);
    const size_t o = ((size_t)b * N_ + n0 + n) * C_ + c0 + cb;
    *(uint4*)&xh[o]     = *(uint4*)&h[0];
    *(uint4*)&xh[o + 8] = *(uint4*)&h[8];
}

__global__ __launch_bounds__(256) void split_w_kernel(
    const float* __restrict__ W, unsigned short* __restrict__ wh)
{
    const int i = (blockIdx.x * 256 + threadIdx.x) * 4;
    float4 v = *(const float4*)&W[i];
    alignas(8) unsigned short h[4];
    h[0] = f16b(v.x); h[1] = f16b(v.y); h[2] = f16b(v.z); h[3] = f16b(v.w);
    *(ushort4*)&wh[i] = *(ushort4*)&h[0];
}

// concat BN params of q, k, v into stacked [1536] arrays
__global__ __launch_bounds__(512) void param_concat_kernel(
    const float* gq, const float* bq, const float* mq, const float* vq,
    const float* gk, const float* bk, const float* mk, const float* vk,
    const float* gv, const float* bv, const float* mv, const float* vv,
    float* sg, float* sb, float* sm, float* sv)
{
    const int i = threadIdx.x;
    sg[i] = gq[i];  sg[512 + i] = gk[i];  sg[1024 + i] = gv[i];
    sb[i] = bq[i];  sb[512 + i] = bk[i];  sb[1024 + i] = bv[i];
    sm[i] = mq[i];  sm[512 + i] = mk[i];  sm[1024 + i] = mv[i];
    sv[i] = vq[i];  sv[512 + i] = vk[i];  sv[1024 + i] = vv[i];
}

// ---------------------------------------------------------------------------
// qk256<EPI>: 256x256 tile, BK=64, 8 waves (2Mx4N, per-wave 128x64),
// 128 KiB double-buffered LDS, counted vmcnt(8), T2 XOR swizzle (128B rows,
// slot ^= row&7 involution on stage source and ds_read), setprio cluster.
// All epilogues route through a [256][264] fp16 LDS repack tile (reusing the
// dead dbuf) -> 16 coalesced uint4 global stores per thread.
// EPI_QK:    A=qT B=kT (stacked, lda/ldb=1024); epilogue exp/stats + p fp16.
// EPI_PROJT: A=stacked [Wq|Wk|Wv] (M=1536, strideA=0), B=xT; BN epilogue.
//            by<4  -> q/k section: fp16 out at qkTh[n*1024 + m]
//            by>=4 -> v section:   fp16 out at vbf[(m-1024)*2048 + n]
// ---------------------------------------------------------------------------
constexpr int EPI_QK = 0, EPI_PROJT = 2;

template <int EPI>
__global__ __launch_bounds__(512, 2) void qk256(
    const unsigned short* __restrict__ Ah, const unsigned short* __restrict__ Bh,
    int K, int lda, int ldb,
    long strideA, long strideB, long strideC, long strideC2,
    void* __restrict__ C0, void* __restrict__ C1, float* __restrict__ ML,
    const float* __restrict__ g, const float* __restrict__ bt,
    const float* __restrict__ mu, const float* __restrict__ var)
{
    // 131072 for the dbuf main loop; 135168 for the [256][264] repack tile.
    __shared__ char smem[135168];

    const int id = blockIdx.x;
    const int bz = id & 7;                 // batch-pinned XCD
    const int s  = id >> 3;
    const int bx = s & 7, by = s >> 3;
    const int n0 = bx * 256;
    const int m0 = by * 256;

    const unsigned short* Ahb = Ah + (size_t)bz * strideA;
    const unsigned short* Bhb = Bh + (size_t)bz * strideB;

    const int tid  = threadIdx.x;
    const int lane = tid & 63;
    const int wv   = tid >> 6;
    const int wr   = wv >> 2, wc = wv & 3;
    const int WRB  = wr * 128, WCB = wc * 64;
    const int l4 = lane >> 4, l15 = lane & 15;

    const int srow  = tid >> 3;                       // 0..63
    const int sslot = ((tid & 7) ^ (srow & 7)) * 8;   // pre-swizzled col

#define STAGE(t)                                                              \
    {                                                                         \
        char* dst = smem + ((t) & 1) * 65536;                                 \
        const unsigned short* asrc =                                          \
            Ahb + (size_t)(m0 + srow) * lda + (t) * 64 + sslot;               \
        _Pragma("unroll")                                                     \
        for (int u = 0; u < 4; ++u)                                           \
            gload_lds16(asrc + (size_t)(u * 64) * lda,                        \
                        dst + u * 8192 + tid * 16);                           \
        const unsigned short* bsrc =                                          \
            Bhb + (size_t)(n0 + srow) * ldb + (t) * 64 + sslot;               \
        _Pragma("unroll")                                                     \
        for (int u = 0; u < 4; ++u)                                           \
            gload_lds16(bsrc + (size_t)(u * 64) * ldb,                        \
                        dst + 32768 + u * 8192 + tid * 16);                   \
    }

    f32x4 acc[8][4] = {};
    const int NT = K / 64;

    STAGE(0);

    for (int t = 0; t < NT; ++t) {
        char* cur = smem + (t & 1) * 65536;
        __builtin_amdgcn_s_barrier();          // buf[(t+1)&1] fully consumed
        if (t + 1 < NT) {
            STAGE(t + 1);
            asm volatile("s_waitcnt vmcnt(8)" ::: "memory");
        } else {
            asm volatile("s_waitcnt vmcnt(0)" ::: "memory");
        }
        __builtin_amdgcn_s_barrier();          // tile t staged by all waves

        f16x8 ah[8][2], bh[4][2];
#pragma unroll
        for (int m = 0; m < 8; ++m) {
            const int row = WRB + m * 16 + l15;
#pragma unroll
            for (int kk = 0; kk < 2; ++kk)
                ah[m][kk] = *(const f16x8*)(cur + row * 128 +
                                            (((kk << 2) | l4) ^ (row & 7)) * 16);
        }
#pragma unroll
        for (int n = 0; n < 4; ++n) {
            const int row = WCB + n * 16 + l15;
#pragma unroll
            for (int kk = 0; kk < 2; ++kk)
                bh[n][kk] = *(const f16x8*)(cur + 32768 + row * 128 +
                                            (((kk << 2) | l4) ^ (row & 7)) * 16);
        }
        __builtin_amdgcn_s_setprio(1);
#pragma unroll
        for (int kk = 0; kk < 2; ++kk)
#pragma unroll
            for (int m = 0; m < 8; ++m)
#pragma unroll
                for (int n = 0; n < 4; ++n)
                    acc[m][n] = __builtin_amdgcn_mfma_f32_16x16x32_f16(
                        ah[m][kk], bh[n][kk], acc[m][n], 0, 0, 0);
        __builtin_amdgcn_s_setprio(0);
    }
#undef STAGE

    __syncthreads();                       // loop drained; dbuf reusable
    unsigned short* plds = (unsigned short*)smem;   // [256][264] fp16

    if constexpr (EPI == EPI_QK) {
        const int tcol = bx * 4 + wc;                     // 64-col tile id
        const size_t mbase = (((size_t)bz * 32 + tcol) * 2) * 2048;
#pragma unroll
        for (int m = 0; m < 8; ++m) {
#pragma unroll
            for (int r = 0; r < 4; ++r) {
                float mx = fmaxf(fmaxf(acc[m][0][r], acc[m][1][r]),
                                 fmaxf(acc[m][2][r], acc[m][3][r]));
#pragma unroll
                for (int off = 1; off < 16; off <<= 1)
                    mx = fmaxf(mx, __shfl_xor(mx, off));
                float pe[4];
                float s2 = 0.f;
#pragma unroll
                for (int n = 0; n < 4; ++n) {
                    pe[n] = __expf(acc[m][n][r] - mx);
                    s2 += pe[n];
                }
#pragma unroll
                for (int off = 1; off < 16; off <<= 1)
                    s2 += __shfl_xor(s2, off);
                const int rloc = WRB + m * 16 + l4 * 4 + r;   // 0..255
                if (l15 == 0) {
                    ML[mbase + m0 + rloc] = mx;
                    ML[mbase + 2048 + m0 + rloc] = s2;
                }
#pragma unroll
                for (int n = 0; n < 4; ++n)
                    plds[rloc * 264 + WCB + n * 16 + l15] = f16b(pe[n]);
            }
        }
        __syncthreads();
        unsigned short* H = (unsigned short*)C0 + (size_t)bz * strideC;
#pragma unroll
        for (int it = 0; it < 16; ++it) {
            const int c = it * 512 + tid;
            const int row = c >> 5, seg = c & 31;
            *(uint4*)&H[(size_t)(m0 + row) * 2048 + n0 + seg * 8] =
                *(const uint4*)&plds[row * 264 + seg * 8];
        }
    } else {  // EPI_PROJT: stacked BN by m; section switch is block-uniform
        if (m0 < 1024) {   // q/k section: out[n*1024 + m], repack [n][m]
#pragma unroll
            for (int m = 0; m < 8; ++m) {
                const int ml = WRB + m * 16 + l4 * 4;     // m_local
                const int mg = m0 + ml;
                float sc[4], sh[4];
#pragma unroll
                for (int r = 0; r < 4; ++r) {
                    const int o = mg + r;
                    sc[r] = g[o] * rsqrtf(var[o] + EPSV);
                    sh[r] = bt[o] - mu[o] * sc[r];
                }
#pragma unroll
                for (int n = 0; n < 4; ++n) {
                    const int nl = WCB + n * 16 + l15;    // n_local
                    alignas(8) unsigned short h4[4];
#pragma unroll
                    for (int r = 0; r < 4; ++r)
                        h4[r] = f16b(acc[m][n][r] * sc[r] + sh[r]);
                    *(ushort4*)&plds[nl * 264 + ml] = *(ushort4*)&h4[0];
                }
            }
            __syncthreads();
            unsigned short* H = (unsigned short*)C0 + (size_t)bz * strideC;
#pragma unroll
            for (int it = 0; it < 16; ++it) {
                const int c = it * 512 + tid;
                const int row = c >> 5, seg = c & 31;     // row=n, seg along m
                *(uint4*)&H[(size_t)(n0 + row) * 1024 + m0 + seg * 8] =
                    *(const uint4*)&plds[row * 264 + seg * 8];
            }
        } else {           // v section: out[(m-1024)*2048 + n], repack [d][j]
#pragma unroll
            for (int m = 0; m < 8; ++m) {
                const int dl = WRB + m * 16 + l4 * 4;     // d_local
                const int mg = m0 + dl;
                float sc[4], sh[4];
#pragma unroll
                for (int r = 0; r < 4; ++r) {
                    const int o = mg + r;
                    sc[r] = g[o] * rsqrtf(var[o] + EPSV);
                    sh[r] = bt[o] - mu[o] * sc[r];
                }
#pragma unroll
                for (int n = 0; n < 4; ++n) {
                    const int jl = WCB + n * 16 + l15;    // j_local
#pragma unroll
                    for (int r = 0; r < 4; ++r)
                        plds[(dl + r) * 264 + jl] =
                            f16b(acc[m][n][r] * sc[r] + sh[r]);
                }
            }
            __syncthreads();
            unsigned short* V = (unsigned short*)C1 + (size_t)bz * strideC2;
#pragma unroll
            for (int it = 0; it < 16; ++it) {
                const int c = it * 512 + tid;
                const int row = c >> 5, seg = c & 31;     // row=d, seg along j
                *(uint4*)&V[(size_t)(m0 - 1024 + row) * 2048 + n0 + seg * 8] =
                    *(const uint4*)&plds[row * 264 + seg * 8];
            }
        }
    }
}

// ---------------------------------------------------------------------------
// PV: 256x128, tri-buffered, counted vmcnt(6) — unchanged from round 12.
// ---------------------------------------------------------------------------
__global__ __launch_bounds__(512, 2) void pv256(
    const unsigned short* __restrict__ Ah, const unsigned short* __restrict__ Bh,
    int K, int lda, int ldb, long strideA, long strideB, long strideC,
    void* __restrict__ C0,
    const float* __restrict__ corr, const float* __restrict__ linv)
{
    constexpr int BUFSZ = 49152;
    __shared__ char smem[163840];

    const int id = blockIdx.x;
    const int bz = id & 7;
    const int s  = id >> 3;
    const int bx = s & 3, by = s >> 2;
    const int n0 = bx * 128;
    const int m0 = by * 256;

    const unsigned short* Ahb = Ah + (size_t)bz * strideA;
    const unsigned short* Bhb = Bh + (size_t)bz * strideB;

    const int tid  = threadIdx.x;
    const int lane = tid & 63;
    const int wv   = tid >> 6;
    const int wr   = wv >> 2, wc = wv & 3;
    const int WRB  = wr * 128, WCB = wc * 32;
    const int l4 = lane >> 4, l15 = lane & 15;

    const int srow = tid >> 3;
    const int sslot = ((tid & 7) ^ (srow & 7)) * 8;

    unsigned short* corrLds = (unsigned short*)(smem + 147456);
    for (int idx = tid; idx < 2048; idx += 512) {
        const int t = idx >> 6, i4 = (idx & 63) * 4;
        float4 c4 = *(const float4*)&corr[((size_t)bz * 32 + t) * 2048 + m0 + i4];
        alignas(8) unsigned short h4[4] =
            {f16b(c4.x), f16b(c4.y), f16b(c4.z), f16b(c4.w)};
        *(ushort4*)&corrLds[(size_t)t * 256 + i4] = *(ushort4*)&h4[0];
    }
    __syncthreads();

#define STAGE(t)                                                              \
    {                                                                         \
        char* dst = smem + ((t) % 3) * BUFSZ;                                 \
        const unsigned short* asrc =                                          \
            Ahb + (size_t)(m0 + srow) * lda + (t) * 64 + sslot;               \
        _Pragma("unroll")                                                     \
        for (int u = 0; u < 4; ++u)                                           \
            gload_lds16(asrc + (size_t)(u * 64) * lda,                        \
                        dst + u * 8192 + tid * 16);                           \
        const unsigned short* bsrc =                                          \
            Bhb + (size_t)(n0 + srow) * ldb + (t) * 64 + sslot;               \
        _Pragma("unroll")                                                     \
        for (int u = 0; u < 2; ++u)                                           \
            gload_lds16(bsrc + (size_t)(u * 64) * ldb,                        \
                        dst + 32768 + u * 8192 + tid * 16);                   \
    }

    f32x4 acc[8][2] = {};
    const int NT = K / 64;

    STAGE(0);
    STAGE(1);

    for (int t = 0; t < NT; ++t) {
        char* cur = smem + (t % 3) * BUFSZ;
        if (t + 2 < NT) {
            asm volatile("s_waitcnt vmcnt(6)" ::: "memory");
        } else {
            asm volatile("s_waitcnt vmcnt(0)" ::: "memory");
        }
        __builtin_amdgcn_s_barrier();
        asm volatile("" ::: "memory");
        if (t + 2 < NT) STAGE(t + 2);

        f16x8 ah[8][2], bh[2][2];
#pragma unroll
        for (int m = 0; m < 8; ++m) {
            const int row = WRB + m * 16 + l15;
#pragma unroll
            for (int kk = 0; kk < 2; ++kk)
                ah[m][kk] = *(const f16x8*)(cur + row * 128 +
                                            (((kk << 2) | l4) ^ (row & 7)) * 16);
        }
#pragma unroll
        for (int n = 0; n < 2; ++n) {
            const int row = WCB + n * 16 + l15;
#pragma unroll
            for (int kk = 0; kk < 2; ++kk)
                bh[n][kk] = *(const f16x8*)(cur + 32768 + row * 128 +
                                            (((kk << 2) | l4) ^ (row & 7)) * 16);
        }
#pragma unroll
        for (int m = 0; m < 8; ++m) {
            const _Float16 cf = ((const _Float16*)corrLds)
                [(size_t)t * 256 + WRB + m * 16 + l15];
            ah[m][0] = ah[m][0] * cf;
            ah[m][1] = ah[m][1] * cf;
        }
        __builtin_amdgcn_s_setprio(1);
#pragma unroll
        for (int kk = 0; kk < 2; ++kk)
#pragma unroll
            for (int m = 0; m < 8; ++m)
#pragma unroll
                for (int n = 0; n < 2; ++n)
                    acc[m][n] = __builtin_amdgcn_mfma_f32_16x16x32_f16(
                        ah[m][kk], bh[n][kk], acc[m][n], 0, 0, 0);
        __builtin_amdgcn_s_setprio(0);
    }
#undef STAGE

    float* Cb = (float*)C0 + (size_t)bz * strideC;
    const float* lb = linv + (size_t)bz * 2048;
#pragma unroll
    for (int m = 0; m < 8; ++m) {
        const int mrow = m0 + WRB + m * 16 + l4 * 4;
        float lv[4];
#pragma unroll
        for (int r = 0; r < 4; ++r)
            lv[r] = lb[mrow + r];
#pragma unroll
        for (int n = 0; n < 2; ++n) {
            const int col = n0 + WCB + n * 16 + l15;
            float4 o4 = make_float4(acc[m][n][0] * lv[0],
                                    acc[m][n][1] * lv[1],
                                    acc[m][n][2] * lv[2],
                                    acc[m][n][3] * lv[3]);
            *(float4*)&Cb[(size_t)col * 2048 + mrow] = o4;
        }
    }
}

// ---------------------------------------------------------------------------
__global__ __launch_bounds__(256) void ml_combine_kernel(
    const float* __restrict__ ml, float* __restrict__ corr,
    float* __restrict__ linv)
{
    const int idx = blockIdx.x * 256 + threadIdx.x;
    const int b = idx >> 11, i = idx & 2047;
    const float* base = ml + ((size_t)b * 32) * 2 * 2048 + i;
    float M = -3.0e38f;
#pragma unroll 8
    for (int t = 0; t < 32; ++t)
        M = fmaxf(M, base[(size_t)t * 4096]);
    float L = 0.f;
    float* cb = corr + (size_t)b * 32 * 2048 + i;
#pragma unroll 8
    for (int t = 0; t < 32; ++t) {
        const float c = __expf(base[(size_t)t * 4096] - M);
        L += c * base[(size_t)t * 4096 + 2048];
        cb[(size_t)t * 2048] = c;
    }
    linv[idx] = 1.0f / L;
}

// ---------------------------------------------------------------------------
extern "C" void kernel_launch(void* const* d_in, const int* in_sizes, int n_in,
                              void* d_out, int out_size, void* d_ws, size_t ws_size,
                              hipStream_t stream)
{
    (void)in_sizes; (void)n_in; (void)out_size; (void)ws_size;
    const float* x  = (const float*)d_in[0];
    const float* Wq = (const float*)d_in[1];
    const float* gq = (const float*)d_in[2];
    const float* bq = (const float*)d_in[3];
    const float* mq = (const float*)d_in[4];
    const float* vq = (const float*)d_in[5];
    const float* Wk = (const float*)d_in[6];
    const float* gk = (const float*)d_in[7];
    const float* bk = (const float*)d_in[8];
    const float* mk = (const float*)d_in[9];
    const float* vk = (const float*)d_in[10];
    const float* Wv = (const float*)d_in[11];
    const float* gv = (const float*)d_in[12];
    const float* bv = (const float*)d_in[13];
    const float* mv = (const float*)d_in[14];
    const float* vv = (const float*)d_in[15];
    float* out = (float*)d_out;

    const size_t MiB = 1048576;
    char* ws = (char*)d_ws;
    // stacked W: [Wq; Wk; Wv] contiguous 1536x512 fp16
    unsigned short* Wst = (unsigned short*)(ws);
    unsigned short* Wqh = Wst;
    unsigned short* Wkh = Wst + 512 * 512;
    unsigned short* Wvh = Wst + 1024 * 512;
    unsigned short* vbf  = (unsigned short*)(ws + 2 * MiB);   // 16 MiB (d,j)
    unsigned short* qkTh = (unsigned short*)(ws + 18 * MiB);  // 32 MiB (n,[q|k])
    unsigned short* xTh  = (unsigned short*)(ws + 50 * MiB);  // 16 MiB (n,c)
    unsigned short* pbuf = (unsigned short*)(ws + 66 * MiB);  // 64 MiB fp16 p
    float* mlbuf = (float*)(ws + 130 * MiB);                  // 4 MiB stats
    float* corr  = (float*)(ws + 134 * MiB);                  // 2 MiB
    float* linv  = (float*)(ws + 136 * MiB);                  // 64 KiB
    float* sg = (float*)(ws + 136 * MiB + 65536);             // 6 KiB each
    float* sb = sg + 1536;
    float* sm = sb + 1536;
    float* sv = sm + 1536;

    const long BS = (long)N_ * C_;              // 1M elems per batch
    const long QKS = (long)N_ * 1024;           // stacked qk per batch

    // --- conversions + param concat ---
    split_x_kernel<<<dim3(N_ / 64, C_ / 64, B_), 256, 0, stream>>>(x, xTh);
    split_w_kernel<<<dim3(256), 256, 0, stream>>>(Wq, Wqh);
    split_w_kernel<<<dim3(256), 256, 0, stream>>>(Wk, Wkh);
    split_w_kernel<<<dim3(256), 256, 0, stream>>>(Wv, Wvh);
    param_concat_kernel<<<dim3(1), 512, 0, stream>>>(
        gq, bq, mq, vq, gk, bk, mk, vk, gv, bv, mv, vv, sg, sb, sm, sv);

    // --- stacked q/k/v projection: M=1536 ([Wq|Wk|Wv]), grid 8*8*6 ---
    qk256<EPI_PROJT><<<dim3(384), 512, 0, stream>>>(
        Wst, xTh, 512, 512, 512, 0, BS, QKS, BS, qkTh, vbf,
        nullptr, sg, sb, sm, sv);

    // --- logits -> p_local fp16 + per-tile stats (256², counted vmcnt) ---
    qk256<EPI_QK><<<dim3(512), 512, 0, stream>>>(
        qkTh, qkTh + 512, 512, 1024, 1024, QKS, QKS, (long)N_ * N_, 0,
        pbuf, nullptr, mlbuf, nullptr, nullptr, nullptr, nullptr);

    // --- combine stats -> corr, linv ---
    ml_combine_kernel<<<dim3(B_ * N_ / 256), 256, 0, stream>>>(
        mlbuf, corr, linv);

    // --- PV (256x128, tri-buffer counted vmcnt, corr-scaled, /l epilogue) ---
    pv256<<<dim3(256), 512, 0, stream>>>(
        pbuf, vbf, 2048, 2048, 2048, (long)N_ * N_, BS, BS, out, corr, linv);
}

// Round 15
// 169.356 us; speedup vs baseline: 1.0674x; 1.0674x over previous
//
#include <hip/hip_runtime.h>
#include <cstdint>
#include <cstddef>

#define EPSV 1e-5f
constexpr int B_ = 8;
constexpr int C_ = 512;
constexpr int N_ = 2048;

typedef _Float16 f16x8 __attribute__((ext_vector_type(8)));
typedef float    f32x4 __attribute__((ext_vector_type(4)));

__device__ __forceinline__ unsigned short f16b(float f) {
    _Float16 h = (_Float16)f;
    return __builtin_bit_cast(unsigned short, h);
}

__device__ __forceinline__ void gload_lds16(const void* g, void* l) {
    __builtin_amdgcn_global_load_lds(
        (const __attribute__((address_space(1))) void*)g,
        (__attribute__((address_space(3))) void*)l, 16, 0, 0);
}

// ---------------------------------------------------------------------------
// x (B,C,N) fp32 -> xT (B,N,C) fp16
// ---------------------------------------------------------------------------
__global__ __launch_bounds__(256) void split_x_kernel(
    const float* __restrict__ x, unsigned short* __restrict__ xh)
{
    __shared__ float T[64][65];
    const int b = blockIdx.z, c0 = blockIdx.y * 64, n0 = blockIdx.x * 64;
    const float* xb = x + ((size_t)b * C_ + c0) * N_ + n0;
    const int tid = threadIdx.x;
    const int lr = tid >> 4;
    const int lcn = (tid & 15) * 4;
#pragma unroll
    for (int it = 0; it < 4; ++it) {
        float4 v = *(const float4*)&xb[(size_t)(lr + 16 * it) * N_ + lcn];
        T[lr + 16 * it][lcn + 0] = v.x;
        T[lr + 16 * it][lcn + 1] = v.y;
        T[lr + 16 * it][lcn + 2] = v.z;
        T[lr + 16 * it][lcn + 3] = v.w;
    }
    __syncthreads();
    const int n = tid >> 2, cb = (tid & 3) * 16;
    alignas(16) unsigned short h[16];
#pragma unroll
    for (int i = 0; i < 16; ++i)
        h[i] = f16b(T[cb + i][n]);
    const size_t o = ((size_t)b * N_ + n0 + n) * C_ + c0 + cb;
    *(uint4*)&xh[o]     = *(uint4*)&h[0];
    *(uint4*)&xh[o + 8] = *(uint4*)&h[8];
}

__global__ __launch_bounds__(256) void split_w_kernel(
    const float* __restrict__ W, unsigned short* __restrict__ wh)
{
    const int i = (blockIdx.x * 256 + threadIdx.x) * 4;
    float4 v = *(const float4*)&W[i];
    alignas(8) unsigned short h[4];
    h[0] = f16b(v.x); h[1] = f16b(v.y); h[2] = f16b(v.z); h[3] = f16b(v.w);
    *(ushort4*)&wh[i] = *(ushort4*)&h[0];
}

// concat BN params of q, k, v into stacked [1536] arrays
__global__ __launch_bounds__(512) void param_concat_kernel(
    const float* gq, const float* bq, const float* mq, const float* vq,
    const float* gk, const float* bk, const float* mk, const float* vk,
    const float* gv, const float* bv, const float* mv, const float* vv,
    float* sg, float* sb, float* sm, float* sv)
{
    const int i = threadIdx.x;
    sg[i] = gq[i];  sg[512 + i] = gk[i];  sg[1024 + i] = gv[i];
    sb[i] = bq[i];  sb[512 + i] = bk[i];  sb[1024 + i] = bv[i];
    sm[i] = mq[i];  sm[512 + i] = mk[i];  sm[1024 + i] = mv[i];
    sv[i] = vq[i];  sv[512 + i] = vk[i];  sv[1024 + i] = vv[i];
}

// ---------------------------------------------------------------------------
// qk256<EPI>: 256x128 tile, BK=32, 8 waves (4Mx2N, per-wave 64x64 -> acc 64
// VGPR), 48 KiB double-buffered LDS -> 2 blocks/CU (16 waves/CU).  2-barrier
// counted-vmcnt schedule; STAGE = 3 loads/thread so the counted wait is
// vmcnt(3) (= loads-per-STAGE x (stages-in-flight - 1); round-14's vmcnt(4)
// left one tile-t load pending -> NaN).  Swizzle for 64B rows:
// slot ^= (row>>1)&3 on BOTH staging source and ds_read (same involution).
// k-accumulation order identical to round 12 -> bit-identical output.
// EPI_QK:    A=qT B=kT (stacked, lda/ldb=1024); exp/stats epilogue; ML
//            layout unchanged (tcol = bx*2 + wc, 32 tiles of 64 cols).
// EPI_PROJT: A=stacked [Wq|Wk|Wv] (M=1536, strideA=0), B=xT; BN epilogue.
//            m0<1024 -> q/k: out at qkTh[n*1024+m]; else v: vbf[(m-1024)*2048+n]
// ---------------------------------------------------------------------------
constexpr int EPI_QK = 0, EPI_PROJT = 2;

template <int EPI>
__global__ __launch_bounds__(512, 4) void qk256(
    const unsigned short* __restrict__ Ah, const unsigned short* __restrict__ Bh,
    int K, int lda, int ldb,
    long strideA, long strideB, long strideC, long strideC2,
    void* __restrict__ C0, void* __restrict__ C1, float* __restrict__ ML,
    const float* __restrict__ g, const float* __restrict__ bt,
    const float* __restrict__ mu, const float* __restrict__ var)
{
    __shared__ char smem[49152];           // 2 x (16KB A + 8KB B)

    const int id = blockIdx.x;
    const int bz = id & 7;                 // batch-pinned XCD
    const int s  = id >> 3;
    const int bx = s & 15, by = s >> 4;
    const int n0 = bx * 128;
    const int m0 = by * 256;

    const unsigned short* Ahb = Ah + (size_t)bz * strideA;
    const unsigned short* Bhb = Bh + (size_t)bz * strideB;

    const int tid  = threadIdx.x;
    const int lane = tid & 63;
    const int wv   = tid >> 6;
    const int wr   = wv >> 1, wc = wv & 1;
    const int WRB  = wr * 64, WCB = wc * 64;
    const int l4 = lane >> 4, l15 = lane & 15;

#define STAGE(t)                                                              \
    {                                                                         \
        char* dst = smem + ((t) & 1) * 24576;                                 \
        _Pragma("unroll")                                                     \
        for (int u = 0; u < 2; ++u) {                                         \
            const int L = u * 512 + tid;                                      \
            const int row = L >> 2;                                           \
            const int ssl = ((L & 3) ^ ((row >> 1) & 3)) * 8;                 \
            gload_lds16(Ahb + (size_t)(m0 + row) * lda + (t) * 32 + ssl,      \
                        dst + L * 16);                                        \
        }                                                                     \
        {                                                                     \
            const int row = tid >> 2;                                         \
            const int ssl = ((tid & 3) ^ ((row >> 1) & 3)) * 8;               \
            gload_lds16(Bhb + (size_t)(n0 + row) * ldb + (t) * 32 + ssl,      \
                        dst + 16384 + tid * 16);                              \
        }                                                                     \
    }

    f32x4 acc[4][4] = {};
    const int NT = K / 32;

    STAGE(0);

    for (int t = 0; t < NT; ++t) {
        char* cur = smem + (t & 1) * 24576;
        __builtin_amdgcn_s_barrier();          // prev buf fully consumed
        if (t + 1 < NT) {
            STAGE(t + 1);
            asm volatile("s_waitcnt vmcnt(3)" ::: "memory");
        } else {
            asm volatile("s_waitcnt vmcnt(0)" ::: "memory");
        }
        __builtin_amdgcn_s_barrier();          // tile t staged by all waves

        f16x8 ah[4], bh[4];
#pragma unroll
        for (int m = 0; m < 4; ++m) {
            const int row = WRB + m * 16 + l15;
            ah[m] = *(const f16x8*)(cur + row * 64 +
                                    ((l4 ^ ((row >> 1) & 3)) * 16));
        }
#pragma unroll
        for (int n = 0; n < 4; ++n) {
            const int row = WCB + n * 16 + l15;
            bh[n] = *(const f16x8*)(cur + 16384 + row * 64 +
                                    ((l4 ^ ((row >> 1) & 3)) * 16));
        }
        __builtin_amdgcn_s_setprio(1);
#pragma unroll
        for (int m = 0; m < 4; ++m)
#pragma unroll
            for (int n = 0; n < 4; ++n)
                acc[m][n] = __builtin_amdgcn_mfma_f32_16x16x32_f16(
                    ah[m], bh[n], acc[m][n], 0, 0, 0);
        __builtin_amdgcn_s_setprio(0);
    }
#undef STAGE

    if constexpr (EPI == EPI_QK) {
        unsigned short* H = (unsigned short*)C0 + (size_t)bz * strideC;
        const int tcol = bx * 2 + wc;                     // 64-col tile id
        const size_t mbase = (((size_t)bz * 32 + tcol) * 2) * 2048;
#pragma unroll
        for (int m = 0; m < 4; ++m) {
#pragma unroll
            for (int r = 0; r < 4; ++r) {
                float mx = fmaxf(fmaxf(acc[m][0][r], acc[m][1][r]),
                                 fmaxf(acc[m][2][r], acc[m][3][r]));
#pragma unroll
                for (int off = 1; off < 16; off <<= 1)
                    mx = fmaxf(mx, __shfl_xor(mx, off));
                float pe[4];
                float s2 = 0.f;
#pragma unroll
                for (int n = 0; n < 4; ++n) {
                    pe[n] = __expf(acc[m][n][r] - mx);
                    s2 += pe[n];
                }
#pragma unroll
                for (int off = 1; off < 16; off <<= 1)
                    s2 += __shfl_xor(s2, off);
                const int rloc = WRB + m * 16 + l4 * 4 + r;   // 0..255
                if (l15 == 0) {
                    ML[mbase + m0 + rloc] = mx;
                    ML[mbase + 2048 + m0 + rloc] = s2;
                }
#pragma unroll
                for (int n = 0; n < 4; ++n)
                    H[(size_t)(m0 + rloc) * 2048 + n0 + WCB + n * 16 + l15] =
                        f16b(pe[n]);
            }
        }
    } else {  // EPI_PROJT: stacked BN by m; section switch is block-uniform
        if (m0 < 1024) {
            unsigned short* H = (unsigned short*)C0 + (size_t)bz * strideC;
#pragma unroll
            for (int m = 0; m < 4; ++m) {
                const int mg = m0 + WRB + m * 16 + l4 * 4;
                float sc[4], sh[4];
#pragma unroll
                for (int r = 0; r < 4; ++r) {
                    const int o = mg + r;
                    sc[r] = g[o] * rsqrtf(var[o] + EPSV);
                    sh[r] = bt[o] - mu[o] * sc[r];
                }
#pragma unroll
                for (int n = 0; n < 4; ++n) {
                    const int ng = n0 + WCB + n * 16 + l15;
                    alignas(8) unsigned short h4[4];
#pragma unroll
                    for (int r = 0; r < 4; ++r)
                        h4[r] = f16b(acc[m][n][r] * sc[r] + sh[r]);
                    *(ushort4*)&H[(size_t)ng * 1024 + mg] = *(ushort4*)&h4[0];
                }
            }
        } else {
            unsigned short* V = (unsigned short*)C1 + (size_t)bz * strideC2;
#pragma unroll
            for (int m = 0; m < 4; ++m) {
                const int mg = m0 + WRB + m * 16 + l4 * 4;
                float sc[4], sh[4];
#pragma unroll
                for (int r = 0; r < 4; ++r) {
                    const int o = mg + r;
                    sc[r] = g[o] * rsqrtf(var[o] + EPSV);
                    sh[r] = bt[o] - mu[o] * sc[r];
                }
                const int d0 = mg - 1024;
#pragma unroll
                for (int n = 0; n < 4; ++n) {
                    const int ng = n0 + WCB + n * 16 + l15;
#pragma unroll
                    for (int r = 0; r < 4; ++r)
                        V[(size_t)(d0 + r) * 2048 + ng] =
                            f16b(acc[m][n][r] * sc[r] + sh[r]);
                }
            }
        }
    }
}

// ---------------------------------------------------------------------------
// PV: 256x128, tri-buffered, counted vmcnt(6) — round-12 code verbatim.
// ---------------------------------------------------------------------------
__global__ __launch_bounds__(512, 2) void pv256(
    const unsigned short* __restrict__ Ah, const unsigned short* __restrict__ Bh,
    int K, int lda, int ldb, long strideA, long strideB, long strideC,
    void* __restrict__ C0,
    const float* __restrict__ corr, const float* __restrict__ linv)
{
    constexpr int BUFSZ = 49152;
    __shared__ char smem[163840];

    const int id = blockIdx.x;
    const int bz = id & 7;
    const int s  = id >> 3;
    const int bx = s & 3, by = s >> 2;
    const int n0 = bx * 128;
    const int m0 = by * 256;

    const unsigned short* Ahb = Ah + (size_t)bz * strideA;
    const unsigned short* Bhb = Bh + (size_t)bz * strideB;

    const int tid  = threadIdx.x;
    const int lane = tid & 63;
    const int wv   = tid >> 6;
    const int wr   = wv >> 2, wc = wv & 3;
    const int WRB  = wr * 128, WCB = wc * 32;
    const int l4 = lane >> 4, l15 = lane & 15;

    const int srow = tid >> 3;
    const int sslot = ((tid & 7) ^ (srow & 7)) * 8;

    unsigned short* corrLds = (unsigned short*)(smem + 147456);
    for (int idx = tid; idx < 2048; idx += 512) {
        const int t = idx >> 6, i4 = (idx & 63) * 4;
        float4 c4 = *(const float4*)&corr[((size_t)bz * 32 + t) * 2048 + m0 + i4];
        alignas(8) unsigned short h4[4] =
            {f16b(c4.x), f16b(c4.y), f16b(c4.z), f16b(c4.w)};
        *(ushort4*)&corrLds[(size_t)t * 256 + i4] = *(ushort4*)&h4[0];
    }
    __syncthreads();

#define STAGE(t)                                                              \
    {                                                                         \
        char* dst = smem + ((t) % 3) * BUFSZ;                                 \
        const unsigned short* asrc =                                          \
            Ahb + (size_t)(m0 + srow) * lda + (t) * 64 + sslot;               \
        _Pragma("unroll")                                                     \
        for (int u = 0; u < 4; ++u)                                           \
            gload_lds16(asrc + (size_t)(u * 64) * lda,                        \
                        dst + u * 8192 + tid * 16);                           \
        const unsigned short* bsrc =                                          \
            Bhb + (size_t)(n0 + srow) * ldb + (t) * 64 + sslot;               \
        _Pragma("unroll")                                                     \
        for (int u = 0; u < 2; ++u)                                           \
            gload_lds16(bsrc + (size_t)(u * 64) * ldb,                        \
                        dst + 32768 + u * 8192 + tid * 16);                   \
    }

    f32x4 acc[8][2] = {};
    const int NT = K / 64;

    STAGE(0);
    STAGE(1);

    for (int t = 0; t < NT; ++t) {
        char* cur = smem + (t % 3) * BUFSZ;
        if (t + 2 < NT) {
            asm volatile("s_waitcnt vmcnt(6)" ::: "memory");
        } else {
            asm volatile("s_waitcnt vmcnt(0)" ::: "memory");
        }
        __builtin_amdgcn_s_barrier();
        asm volatile("" ::: "memory");
        if (t + 2 < NT) STAGE(t + 2);

        f16x8 ah[8][2], bh[2][2];
#pragma unroll
        for (int m = 0; m < 8; ++m) {
            const int row = WRB + m * 16 + l15;
#pragma unroll
            for (int kk = 0; kk < 2; ++kk)
                ah[m][kk] = *(const f16x8*)(cur + row * 128 +
                                            (((kk << 2) | l4) ^ (row & 7)) * 16);
        }
#pragma unroll
        for (int n = 0; n < 2; ++n) {
            const int row = WCB + n * 16 + l15;
#pragma unroll
            for (int kk = 0; kk < 2; ++kk)
                bh[n][kk] = *(const f16x8*)(cur + 32768 + row * 128 +
                                            (((kk << 2) | l4) ^ (row & 7)) * 16);
        }
#pragma unroll
        for (int m = 0; m < 8; ++m) {
            const _Float16 cf = ((const _Float16*)corrLds)
                [(size_t)t * 256 + WRB + m * 16 + l15];
            ah[m][0] = ah[m][0] * cf;
            ah[m][1] = ah[m][1] * cf;
        }
        __builtin_amdgcn_s_setprio(1);
#pragma unroll
        for (int kk = 0; kk < 2; ++kk)
#pragma unroll
            for (int m = 0; m < 8; ++m)
#pragma unroll
                for (int n = 0; n < 2; ++n)
                    acc[m][n] = __builtin_amdgcn_mfma_f32_16x16x32_f16(
                        ah[m][kk], bh[n][kk], acc[m][n], 0, 0, 0);
        __builtin_amdgcn_s_setprio(0);
    }
#undef STAGE

    float* Cb = (float*)C0 + (size_t)bz * strideC;
    const float* lb = linv + (size_t)bz * 2048;
#pragma unroll
    for (int m = 0; m < 8; ++m) {
        const int mrow = m0 + WRB + m * 16 + l4 * 4;
        float lv[4];
#pragma unroll
        for (int r = 0; r < 4; ++r)
            lv[r] = lb[mrow + r];
#pragma unroll
        for (int n = 0; n < 2; ++n) {
            const int col = n0 + WCB + n * 16 + l15;
            float4 o4 = make_float4(acc[m][n][0] * lv[0],
                                    acc[m][n][1] * lv[1],
                                    acc[m][n][2] * lv[2],
                                    acc[m][n][3] * lv[3]);
            *(float4*)&Cb[(size_t)col * 2048 + mrow] = o4;
        }
    }
}

// ---------------------------------------------------------------------------
__global__ __launch_bounds__(256) void ml_combine_kernel(
    const float* __restrict__ ml, float* __restrict__ corr,
    float* __restrict__ linv)
{
    const int idx = blockIdx.x * 256 + threadIdx.x;
    const int b = idx >> 11, i = idx & 2047;
    const float* base = ml + ((size_t)b * 32) * 2 * 2048 + i;
    float M = -3.0e38f;
#pragma unroll 8
    for (int t = 0; t < 32; ++t)
        M = fmaxf(M, base[(size_t)t * 4096]);
    float L = 0.f;
    float* cb = corr + (size_t)b * 32 * 2048 + i;
#pragma unroll 8
    for (int t = 0; t < 32; ++t) {
        const float c = __expf(base[(size_t)t * 4096] - M);
        L += c * base[(size_t)t * 4096 + 2048];
        cb[(size_t)t * 2048] = c;
    }
    linv[idx] = 1.0f / L;
}

// ---------------------------------------------------------------------------
extern "C" void kernel_launch(void* const* d_in, const int* in_sizes, int n_in,
                              void* d_out, int out_size, void* d_ws, size_t ws_size,
                              hipStream_t stream)
{
    (void)in_sizes; (void)n_in; (void)out_size; (void)ws_size;
    const float* x  = (const float*)d_in[0];
    const float* Wq = (const float*)d_in[1];
    const float* gq = (const float*)d_in[2];
    const float* bq = (const float*)d_in[3];
    const float* mq = (const float*)d_in[4];
    const float* vq = (const float*)d_in[5];
    const float* Wk = (const float*)d_in[6];
    const float* gk = (const float*)d_in[7];
    const float* bk = (const float*)d_in[8];
    const float* mk = (const float*)d_in[9];
    const float* vk = (const float*)d_in[10];
    const float* Wv = (const float*)d_in[11];
    const float* gv = (const float*)d_in[12];
    const float* bv = (const float*)d_in[13];
    const float* mv = (const float*)d_in[14];
    const float* vv = (const float*)d_in[15];
    float* out = (float*)d_out;

    const size_t MiB = 1048576;
    char* ws = (char*)d_ws;
    // stacked W: [Wq; Wk; Wv] contiguous 1536x512 fp16
    unsigned short* Wst = (unsigned short*)(ws);
    unsigned short* Wqh = Wst;
    unsigned short* Wkh = Wst + 512 * 512;
    unsigned short* Wvh = Wst + 1024 * 512;
    unsigned short* vbf  = (unsigned short*)(ws + 2 * MiB);   // 16 MiB (d,j)
    unsigned short* qkTh = (unsigned short*)(ws + 18 * MiB);  // 32 MiB (n,[q|k])
    unsigned short* xTh  = (unsigned short*)(ws + 50 * MiB);  // 16 MiB (n,c)
    unsigned short* pbuf = (unsigned short*)(ws + 66 * MiB);  // 64 MiB fp16 p
    float* mlbuf = (float*)(ws + 130 * MiB);                  // 4 MiB stats
    float* corr  = (float*)(ws + 134 * MiB);                  // 2 MiB
    float* linv  = (float*)(ws + 136 * MiB);                  // 64 KiB
    float* sg = (float*)(ws + 136 * MiB + 65536);             // 6 KiB each
    float* sb = sg + 1536;
    float* sm = sb + 1536;
    float* sv = sm + 1536;

    const long BS = (long)N_ * C_;              // 1M elems per batch
    const long QKS = (long)N_ * 1024;           // stacked qk per batch

    // --- conversions + param concat ---
    split_x_kernel<<<dim3(N_ / 64, C_ / 64, B_), 256, 0, stream>>>(x, xTh);
    split_w_kernel<<<dim3(256), 256, 0, stream>>>(Wq, Wqh);
    split_w_kernel<<<dim3(256), 256, 0, stream>>>(Wk, Wkh);
    split_w_kernel<<<dim3(256), 256, 0, stream>>>(Wv, Wvh);
    param_concat_kernel<<<dim3(1), 512, 0, stream>>>(
        gq, bq, mq, vq, gk, bk, mk, vk, gv, bv, mv, vv, sg, sb, sm, sv);

    // --- stacked q/k/v projection: M=1536, tiles 256x128 -> grid 6*16*8 ---
    qk256<EPI_PROJT><<<dim3(768), 512, 0, stream>>>(
        Wst, xTh, 512, 512, 512, 0, BS, QKS, BS, qkTh, vbf,
        nullptr, sg, sb, sm, sv);

    // --- logits -> p_local fp16 + per-tile stats: grid 8*16*8 ---
    qk256<EPI_QK><<<dim3(1024), 512, 0, stream>>>(
        qkTh, qkTh + 512, 512, 1024, 1024, QKS, QKS, (long)N_ * N_, 0,
        pbuf, nullptr, mlbuf, nullptr, nullptr, nullptr, nullptr);

    // --- combine stats -> corr, linv ---
    ml_combine_kernel<<<dim3(B_ * N_ / 256), 256, 0, stream>>>(
        mlbuf, corr, linv);

    // --- PV (256x128, tri-buffer counted vmcnt, corr-scaled, /l epilogue) ---
    pv256<<<dim3(256), 512, 0, stream>>>(
        pbuf, vbf, 2048, 2048, 2048, (long)N_ * N_, BS, BS, out, corr, linv);
}

// Round 16
// 158.016 us; speedup vs baseline: 1.1440x; 1.0718x over previous
//
#include <hip/hip_runtime.h>
#include <cstdint>
#include <cstddef>

#define EPSV 1e-5f
constexpr int B_ = 8;
constexpr int C_ = 512;
constexpr int N_ = 2048;

typedef _Float16 f16x8 __attribute__((ext_vector_type(8)));
typedef float    f32x4 __attribute__((ext_vector_type(4)));

__device__ __forceinline__ unsigned short f16b(float f) {
    _Float16 h = (_Float16)f;
    return __builtin_bit_cast(unsigned short, h);
}

__device__ __forceinline__ void gload_lds16(const void* g, void* l) {
    __builtin_amdgcn_global_load_lds(
        (const __attribute__((address_space(1))) void*)g,
        (__attribute__((address_space(3))) void*)l, 16, 0, 0);
}

// ---------------------------------------------------------------------------
// x (B,C,N) fp32 -> xT (B,N,C) fp16
// ---------------------------------------------------------------------------
__global__ __launch_bounds__(256) void split_x_kernel(
    const float* __restrict__ x, unsigned short* __restrict__ xh)
{
    __shared__ float T[64][65];
    const int b = blockIdx.z, c0 = blockIdx.y * 64, n0 = blockIdx.x * 64;
    const float* xb = x + ((size_t)b * C_ + c0) * N_ + n0;
    const int tid = threadIdx.x;
    const int lr = tid >> 4;
    const int lcn = (tid & 15) * 4;
#pragma unroll
    for (int it = 0; it < 4; ++it) {
        float4 v = *(const float4*)&xb[(size_t)(lr + 16 * it) * N_ + lcn];
        T[lr + 16 * it][lcn + 0] = v.x;
        T[lr + 16 * it][lcn + 1] = v.y;
        T[lr + 16 * it][lcn + 2] = v.z;
        T[lr + 16 * it][lcn + 3] = v.w;
    }
    __syncthreads();
    const int n = tid >> 2, cb = (tid & 3) * 16;
    alignas(16) unsigned short h[16];
#pragma unroll
    for (int i = 0; i < 16; ++i)
        h[i] = f16b(T[cb + i][n]);
    const size_t o = ((size_t)b * N_ + n0 + n) * C_ + c0 + cb;
    *(uint4*)&xh[o]     = *(uint4*)&h[0];
    *(uint4*)&xh[o + 8] = *(uint4*)&h[8];
}

// ---------------------------------------------------------------------------
// Merged: convert Wq/Wk/Wv -> stacked fp16 [1536][512] AND concat BN params
// into stacked [1536] arrays.  Blocks 0..767 convert W; block 768 does params.
// ---------------------------------------------------------------------------
__global__ __launch_bounds__(256) void split_w_all_kernel(
    const float* __restrict__ Wq, const float* __restrict__ Wk,
    const float* __restrict__ Wv, unsigned short* __restrict__ wst,
    const float* gq, const float* bq, const float* mq, const float* vq,
    const float* gk, const float* bk, const float* mk, const float* vk,
    const float* gv, const float* bv, const float* mv, const float* vv,
    float* sg, float* sb, float* sm, float* sv)
{
    const int blk = blockIdx.x;
    if (blk < 768) {
        const int i = blk * 1024 + threadIdx.x * 4;     // 0..786431
        const int which = i >> 18;                      // 0..2
        const int off = i & 262143;
        const float* W = (which == 0) ? Wq : (which == 1) ? Wk : Wv;
        float4 v = *(const float4*)&W[off];
        alignas(8) unsigned short h[4];
        h[0] = f16b(v.x); h[1] = f16b(v.y); h[2] = f16b(v.z); h[3] = f16b(v.w);
        *(ushort4*)&wst[i] = *(ushort4*)&h[0];
    } else {
#pragma unroll
        for (int u = 0; u < 2; ++u) {
            const int i = threadIdx.x + u * 256;        // 0..511
            sg[i] = gq[i];  sg[512 + i] = gk[i];  sg[1024 + i] = gv[i];
            sb[i] = bq[i];  sb[512 + i] = bk[i];  sb[1024 + i] = bv[i];
            sm[i] = mq[i];  sm[512 + i] = mk[i];  sm[1024 + i] = mv[i];
            sv[i] = vq[i];  sv[512 + i] = vk[i];  sv[1024 + i] = vv[i];
        }
    }
}

// ---------------------------------------------------------------------------
// qk256<EPI>: 256x128 tile, BK=32, 8 waves (4Mx2N, per-wave 64x64), 48 KiB
// dbuf LDS -> 2 blocks/CU.  2-barrier counted-vmcnt(3) (3 loads/STAGE).
// Swizzle for 64B rows: slot ^= (row>>1)&3 on stage source and ds_read.
// (round-15 kernel verbatim — verified, absmax 0.0859375)
// ---------------------------------------------------------------------------
constexpr int EPI_QK = 0, EPI_PROJT = 2;

template <int EPI>
__global__ __launch_bounds__(512, 4) void qk256(
    const unsigned short* __restrict__ Ah, const unsigned short* __restrict__ Bh,
    int K, int lda, int ldb,
    long strideA, long strideB, long strideC, long strideC2,
    void* __restrict__ C0, void* __restrict__ C1, float* __restrict__ ML,
    const float* __restrict__ g, const float* __restrict__ bt,
    const float* __restrict__ mu, const float* __restrict__ var)
{
    __shared__ char smem[49152];           // 2 x (16KB A + 8KB B)

    const int id = blockIdx.x;
    const int bz = id & 7;                 // batch-pinned XCD
    const int s  = id >> 3;
    const int bx = s & 15, by = s >> 4;
    const int n0 = bx * 128;
    const int m0 = by * 256;

    const unsigned short* Ahb = Ah + (size_t)bz * strideA;
    const unsigned short* Bhb = Bh + (size_t)bz * strideB;

    const int tid  = threadIdx.x;
    const int lane = tid & 63;
    const int wv   = tid >> 6;
    const int wr   = wv >> 1, wc = wv & 1;
    const int WRB  = wr * 64, WCB = wc * 64;
    const int l4 = lane >> 4, l15 = lane & 15;

#define STAGE(t)                                                              \
    {                                                                         \
        char* dst = smem + ((t) & 1) * 24576;                                 \
        _Pragma("unroll")                                                     \
        for (int u = 0; u < 2; ++u) {                                         \
            const int L = u * 512 + tid;                                      \
            const int row = L >> 2;                                           \
            const int ssl = ((L & 3) ^ ((row >> 1) & 3)) * 8;                 \
            gload_lds16(Ahb + (size_t)(m0 + row) * lda + (t) * 32 + ssl,      \
                        dst + L * 16);                                        \
        }                                                                     \
        {                                                                     \
            const int row = tid >> 2;                                         \
            const int ssl = ((tid & 3) ^ ((row >> 1) & 3)) * 8;               \
            gload_lds16(Bhb + (size_t)(n0 + row) * ldb + (t) * 32 + ssl,      \
                        dst + 16384 + tid * 16);                              \
        }                                                                     \
    }

    f32x4 acc[4][4] = {};
    const int NT = K / 32;

    STAGE(0);

    for (int t = 0; t < NT; ++t) {
        char* cur = smem + (t & 1) * 24576;
        __builtin_amdgcn_s_barrier();          // prev buf fully consumed
        if (t + 1 < NT) {
            STAGE(t + 1);
            asm volatile("s_waitcnt vmcnt(3)" ::: "memory");
        } else {
            asm volatile("s_waitcnt vmcnt(0)" ::: "memory");
        }
        __builtin_amdgcn_s_barrier();          // tile t staged by all waves

        f16x8 ah[4], bh[4];
#pragma unroll
        for (int m = 0; m < 4; ++m) {
            const int row = WRB + m * 16 + l15;
            ah[m] = *(const f16x8*)(cur + row * 64 +
                                    ((l4 ^ ((row >> 1) & 3)) * 16));
        }
#pragma unroll
        for (int n = 0; n < 4; ++n) {
            const int row = WCB + n * 16 + l15;
            bh[n] = *(const f16x8*)(cur + 16384 + row * 64 +
                                    ((l4 ^ ((row >> 1) & 3)) * 16));
        }
        __builtin_amdgcn_s_setprio(1);
#pragma unroll
        for (int m = 0; m < 4; ++m)
#pragma unroll
            for (int n = 0; n < 4; ++n)
                acc[m][n] = __builtin_amdgcn_mfma_f32_16x16x32_f16(
                    ah[m], bh[n], acc[m][n], 0, 0, 0);
        __builtin_amdgcn_s_setprio(0);
    }
#undef STAGE

    if constexpr (EPI == EPI_QK) {
        unsigned short* H = (unsigned short*)C0 + (size_t)bz * strideC;
        const int tcol = bx * 2 + wc;                     // 64-col tile id
        const size_t mbase = (((size_t)bz * 32 + tcol) * 2) * 2048;
#pragma unroll
        for (int m = 0; m < 4; ++m) {
#pragma unroll
            for (int r = 0; r < 4; ++r) {
                float mx = fmaxf(fmaxf(acc[m][0][r], acc[m][1][r]),
                                 fmaxf(acc[m][2][r], acc[m][3][r]));
#pragma unroll
                for (int off = 1; off < 16; off <<= 1)
                    mx = fmaxf(mx, __shfl_xor(mx, off));
                float pe[4];
                float s2 = 0.f;
#pragma unroll
                for (int n = 0; n < 4; ++n) {
                    pe[n] = __expf(acc[m][n][r] - mx);
                    s2 += pe[n];
                }
#pragma unroll
                for (int off = 1; off < 16; off <<= 1)
                    s2 += __shfl_xor(s2, off);
                const int rloc = WRB + m * 16 + l4 * 4 + r;   // 0..255
                if (l15 == 0) {
                    ML[mbase + m0 + rloc] = mx;
                    ML[mbase + 2048 + m0 + rloc] = s2;
                }
#pragma unroll
                for (int n = 0; n < 4; ++n)
                    H[(size_t)(m0 + rloc) * 2048 + n0 + WCB + n * 16 + l15] =
                        f16b(pe[n]);
            }
        }
    } else {  // EPI_PROJT: stacked BN by m; section switch is block-uniform
        if (m0 < 1024) {
            unsigned short* H = (unsigned short*)C0 + (size_t)bz * strideC;
#pragma unroll
            for (int m = 0; m < 4; ++m) {
                const int mg = m0 + WRB + m * 16 + l4 * 4;
                float sc[4], sh[4];
#pragma unroll
                for (int r = 0; r < 4; ++r) {
                    const int o = mg + r;
                    sc[r] = g[o] * rsqrtf(var[o] + EPSV);
                    sh[r] = bt[o] - mu[o] * sc[r];
                }
#pragma unroll
                for (int n = 0; n < 4; ++n) {
                    const int ng = n0 + WCB + n * 16 + l15;
                    alignas(8) unsigned short h4[4];
#pragma unroll
                    for (int r = 0; r < 4; ++r)
                        h4[r] = f16b(acc[m][n][r] * sc[r] + sh[r]);
                    *(ushort4*)&H[(size_t)ng * 1024 + mg] = *(ushort4*)&h4[0];
                }
            }
        } else {
            unsigned short* V = (unsigned short*)C1 + (size_t)bz * strideC2;
#pragma unroll
            for (int m = 0; m < 4; ++m) {
                const int mg = m0 + WRB + m * 16 + l4 * 4;
                float sc[4], sh[4];
#pragma unroll
                for (int r = 0; r < 4; ++r) {
                    const int o = mg + r;
                    sc[r] = g[o] * rsqrtf(var[o] + EPSV);
                    sh[r] = bt[o] - mu[o] * sc[r];
                }
                const int d0 = mg - 1024;
#pragma unroll
                for (int n = 0; n < 4; ++n) {
                    const int ng = n0 + WCB + n * 16 + l15;
#pragma unroll
                    for (int r = 0; r < 4; ++r)
                        V[(size_t)(d0 + r) * 2048 + ng] =
                            f16b(acc[m][n][r] * sc[r] + sh[r]);
                }
            }
        }
    }
}

// ---------------------------------------------------------------------------
// pv128: 128i x 128d tile, BK=64, 4 waves (2Mx2N, per-wave 64x64), 64 KiB
// dbuf + 8 KiB corr = 72 KiB -> 2 blocks/CU; grid 512 (2/CU: independent
// blocks overlap each other's barrier drains).  Counted vmcnt(8) (= 8
// loads/STAGE).  128B-row swizzle (row&7 involution, proven in r10/r12).
// A = p (corr-scaled per 64-K-tile), B = v; epilogue * linv; fp32 out (d,i).
// Per-output k order: t(0..31) x kk(0..1) — identical to prior PV.
// ---------------------------------------------------------------------------
__global__ __launch_bounds__(256, 2) void pv128(
    const unsigned short* __restrict__ Ah, const unsigned short* __restrict__ Bh,
    int K, int lda, int ldb, long strideA, long strideB, long strideC,
    void* __restrict__ C0,
    const float* __restrict__ corr, const float* __restrict__ linv)
{
    __shared__ char smem[73728];           // 2 x 32KB dbuf + 8KB corr

    const int id = blockIdx.x;
    const int bz = id & 7;                 // batch-pinned XCD
    const int s  = id >> 3;
    const int bx = s & 3, by = s >> 2;     // 4 d-tiles x 16 i-tiles
    const int n0 = bx * 128;
    const int m0 = by * 128;

    const unsigned short* Ahb = Ah + (size_t)bz * strideA;
    const unsigned short* Bhb = Bh + (size_t)bz * strideB;

    const int tid  = threadIdx.x;
    const int lane = tid & 63;
    const int wv   = tid >> 6;
    const int wr   = wv >> 1, wc = wv & 1;
    const int WRB  = wr * 64, WCB = wc * 64;
    const int l4 = lane >> 4, l15 = lane & 15;

    const int NT = K / 64;                 // 32

    // corr preload: [32 t][128 i] fp16 (8 KiB)
    unsigned short* corrLds = (unsigned short*)(smem + 65536);
#pragma unroll
    for (int u = 0; u < 4; ++u) {
        const int idx = u * 256 + tid;     // 0..1023
        const int t = idx >> 5, i4 = (idx & 31) * 4;
        float4 c4 = *(const float4*)&corr[((size_t)bz * 32 + t) * 2048 + m0 + i4];
        alignas(8) unsigned short h4[4] =
            {f16b(c4.x), f16b(c4.y), f16b(c4.z), f16b(c4.w)};
        *(ushort4*)&corrLds[(size_t)t * 128 + i4] = *(ushort4*)&h4[0];
    }
    __syncthreads();

#define STAGE(t)                                                              \
    {                                                                         \
        char* dst = smem + ((t) & 1) * 32768;                                 \
        _Pragma("unroll")                                                     \
        for (int u = 0; u < 4; ++u) {                                         \
            const int L = u * 256 + tid;                                      \
            const int row = L >> 3;                                           \
            const int ssl = ((L & 7) ^ (row & 7)) * 8;                        \
            gload_lds16(Ahb + (size_t)(m0 + row) * lda + (t) * 64 + ssl,      \
                        dst + L * 16);                                        \
        }                                                                     \
        _Pragma("unroll")                                                     \
        for (int u = 0; u < 4; ++u) {                                         \
            const int L = u * 256 + tid;                                      \
            const int row = L >> 3;                                           \
            const int ssl = ((L & 7) ^ (row & 7)) * 8;                        \
            gload_lds16(Bhb + (size_t)(n0 + row) * ldb + (t) * 64 + ssl,      \
                        dst + 16384 + L * 16);                                \
        }                                                                     \
    }

    f32x4 acc[4][4] = {};

    STAGE(0);

    for (int t = 0; t < NT; ++t) {
        char* cur = smem + (t & 1) * 32768;
        __builtin_amdgcn_s_barrier();          // prev buf fully consumed
        if (t + 1 < NT) {
            STAGE(t + 1);
            asm volatile("s_waitcnt vmcnt(8)" ::: "memory");
        } else {
            asm volatile("s_waitcnt vmcnt(0)" ::: "memory");
        }
        __builtin_amdgcn_s_barrier();          // tile t staged by all waves

        f16x8 ah[4][2], bh[4][2];
#pragma unroll
        for (int m = 0; m < 4; ++m) {
            const int row = WRB + m * 16 + l15;
#pragma unroll
            for (int kk = 0; kk < 2; ++kk)
                ah[m][kk] = *(const f16x8*)(cur + row * 128 +
                                            (((kk << 2) | l4) ^ (row & 7)) * 16);
        }
#pragma unroll
        for (int n = 0; n < 4; ++n) {
            const int row = WCB + n * 16 + l15;
#pragma unroll
            for (int kk = 0; kk < 2; ++kk)
                bh[n][kk] = *(const f16x8*)(cur + 16384 + row * 128 +
                                            (((kk << 2) | l4) ^ (row & 7)) * 16);
        }
#pragma unroll
        for (int m = 0; m < 4; ++m) {
            const _Float16 cf = ((const _Float16*)corrLds)
                [(size_t)t * 128 + WRB + m * 16 + l15];
            ah[m][0] = ah[m][0] * cf;
            ah[m][1] = ah[m][1] * cf;
        }
        __builtin_amdgcn_s_setprio(1);
#pragma unroll
        for (int kk = 0; kk < 2; ++kk)
#pragma unroll
            for (int m = 0; m < 4; ++m)
#pragma unroll
                for (int n = 0; n < 4; ++n)
                    acc[m][n] = __builtin_amdgcn_mfma_f32_16x16x32_f16(
                        ah[m][kk], bh[n][kk], acc[m][n], 0, 0, 0);
        __builtin_amdgcn_s_setprio(0);
    }
#undef STAGE

    float* Cb = (float*)C0 + (size_t)bz * strideC;
    const float* lb = linv + (size_t)bz * 2048;
#pragma unroll
    for (int m = 0; m < 4; ++m) {
        const int mrow = m0 + WRB + m * 16 + l4 * 4;
        float lv[4];
#pragma unroll
        for (int r = 0; r < 4; ++r)
            lv[r] = lb[mrow + r];
#pragma unroll
        for (int n = 0; n < 4; ++n) {
            const int col = n0 + WCB + n * 16 + l15;
            float4 o4 = make_float4(acc[m][n][0] * lv[0],
                                    acc[m][n][1] * lv[1],
                                    acc[m][n][2] * lv[2],
                                    acc[m][n][3] * lv[3]);
            *(float4*)&Cb[(size_t)col * 2048 + mrow] = o4;
        }
    }
}

// ---------------------------------------------------------------------------
__global__ __launch_bounds__(256) void ml_combine_kernel(
    const float* __restrict__ ml, float* __restrict__ corr,
    float* __restrict__ linv)
{
    const int idx = blockIdx.x * 256 + threadIdx.x;
    const int b = idx >> 11, i = idx & 2047;
    const float* base = ml + ((size_t)b * 32) * 2 * 2048 + i;
    float M = -3.0e38f;
#pragma unroll 8
    for (int t = 0; t < 32; ++t)
        M = fmaxf(M, base[(size_t)t * 4096]);
    float L = 0.f;
    float* cb = corr + (size_t)b * 32 * 2048 + i;
#pragma unroll 8
    for (int t = 0; t < 32; ++t) {
        const float c = __expf(base[(size_t)t * 4096] - M);
        L += c * base[(size_t)t * 4096 + 2048];
        cb[(size_t)t * 2048] = c;
    }
    linv[idx] = 1.0f / L;
}

// ---------------------------------------------------------------------------
extern "C" void kernel_launch(void* const* d_in, const int* in_sizes, int n_in,
                              void* d_out, int out_size, void* d_ws, size_t ws_size,
                              hipStream_t stream)
{
    (void)in_sizes; (void)n_in; (void)out_size; (void)ws_size;
    const float* x  = (const float*)d_in[0];
    const float* Wq = (const float*)d_in[1];
    const float* gq = (const float*)d_in[2];
    const float* bq = (const float*)d_in[3];
    const float* mq = (const float*)d_in[4];
    const float* vq = (const float*)d_in[5];
    const float* Wk = (const float*)d_in[6];
    const float* gk = (const float*)d_in[7];
    const float* bk = (const float*)d_in[8];
    const float* mk = (const float*)d_in[9];
    const float* vk = (const float*)d_in[10];
    const float* Wv = (const float*)d_in[11];
    const float* gv = (const float*)d_in[12];
    const float* bv = (const float*)d_in[13];
    const float* mv = (const float*)d_in[14];
    const float* vv = (const float*)d_in[15];
    float* out = (float*)d_out;

    const size_t MiB = 1048576;
    char* ws = (char*)d_ws;
    unsigned short* Wst = (unsigned short*)(ws);              // 1536x512 fp16
    unsigned short* vbf  = (unsigned short*)(ws + 2 * MiB);   // 16 MiB (d,j)
    unsigned short* qkTh = (unsigned short*)(ws + 18 * MiB);  // 32 MiB (n,[q|k])
    unsigned short* xTh  = (unsigned short*)(ws + 50 * MiB);  // 16 MiB (n,c)
    unsigned short* pbuf = (unsigned short*)(ws + 66 * MiB);  // 64 MiB fp16 p
    float* mlbuf = (float*)(ws + 130 * MiB);                  // 4 MiB stats
    float* corr  = (float*)(ws + 134 * MiB);                  // 2 MiB
    float* linv  = (float*)(ws + 136 * MiB);                  // 64 KiB
    float* sg = (float*)(ws + 136 * MiB + 65536);             // 6 KiB each
    float* sb = sg + 1536;
    float* sm = sb + 1536;
    float* sv = sm + 1536;

    const long BS = (long)N_ * C_;              // 1M elems per batch
    const long QKS = (long)N_ * 1024;           // stacked qk per batch

    // --- conversions + param concat ---
    split_x_kernel<<<dim3(N_ / 64, C_ / 64, B_), 256, 0, stream>>>(x, xTh);
    split_w_all_kernel<<<dim3(769), 256, 0, stream>>>(
        Wq, Wk, Wv, Wst,
        gq, bq, mq, vq, gk, bk, mk, vk, gv, bv, mv, vv, sg, sb, sm, sv);

    // --- stacked q/k/v projection: M=1536, tiles 256x128 -> grid 6*16*8 ---
    qk256<EPI_PROJT><<<dim3(768), 512, 0, stream>>>(
        Wst, xTh, 512, 512, 512, 0, BS, QKS, BS, qkTh, vbf,
        nullptr, sg, sb, sm, sv);

    // --- logits -> p_local fp16 + per-tile stats: grid 8*16*8 ---
    qk256<EPI_QK><<<dim3(1024), 512, 0, stream>>>(
        qkTh, qkTh + 512, 512, 1024, 1024, QKS, QKS, (long)N_ * N_, 0,
        pbuf, nullptr, mlbuf, nullptr, nullptr, nullptr, nullptr);

    // --- combine stats -> corr, linv ---
    ml_combine_kernel<<<dim3(B_ * N_ / 256), 256, 0, stream>>>(
        mlbuf, corr, linv);

    // --- PV (128x128, 2 blocks/CU, counted vmcnt(8), corr-scaled, /l) ---
    pv128<<<dim3(512), 256, 0, stream>>>(
        pbuf, vbf, 2048, 2048, 2048, (long)N_ * N_, BS, BS, out, corr, linv);
}